// Round 10
// baseline (55418.488 us; speedup 1.0000x reference)
//
#include <hip/hip_runtime.h>

#define BB 128
#define TT 1024
#define INP 54
#define HUM 64
#define NPSI 96540
#define OFF_BH 65536
#define OFF_WIH 65792
#define OFF_C 79616
#define OFF_D 96000
#define OUT_MU 8388608
#define OUT_LS 8390656
#define OUT_HL 8392704

typedef unsigned int u32;
typedef unsigned short u16;
typedef unsigned long long u64;
typedef _Float16 h2 __attribute__((ext_vector_type(2)));

__device__ __forceinline__ u32 pk(float a, float b) {
    h2 v; v.x = (_Float16)a; v.y = (_Float16)b;
    return __builtin_bit_cast(u32, v);
}
__device__ __forceinline__ float f16tof(u16 v) {
    return (float)__builtin_bit_cast(_Float16, v);
}
__device__ __forceinline__ u16 ftof16(float v) {
    return __builtin_bit_cast(u16, (_Float16)v);
}
__device__ __forceinline__ float lo16f(u32 v) { return f16tof((u16)(v & 0xffffu)); }
__device__ __forceinline__ float hi16f(u32 v) { return f16tof((u16)(v >> 16)); }
__device__ __forceinline__ h2 bch2(u32 a) { return __builtin_bit_cast(h2, a); }
__device__ __forceinline__ float fd2(u32 a, u32 b, float c) {
#if __has_builtin(__builtin_amdgcn_fdot2)
    return __builtin_amdgcn_fdot2(bch2(a), bch2(b), c, false);
#else
    return c + lo16f(a) * lo16f(b) + hi16f(a) * hi16f(b);
#endif
}
__device__ __forceinline__ float fsig(float x) { return 1.f / (1.f + __expf(-x)); }
__device__ __forceinline__ float ftanh(float x) { float e = __expf(2.f * x); return 1.f - 2.f / (e + 1.f); }

__device__ __forceinline__ float qred(float v) {
#if __has_builtin(__builtin_amdgcn_mov_dpp)
    int x = __builtin_bit_cast(int, v);
    v += __builtin_bit_cast(float, __builtin_amdgcn_mov_dpp(x, 0xB1, 0xF, 0xF, true)); // [1,0,3,2]
    x = __builtin_bit_cast(int, v);
    v += __builtin_bit_cast(float, __builtin_amdgcn_mov_dpp(x, 0x4E, 0xF, 0xF, true)); // [2,3,0,1]
    return v;
#else
    v += __shfl_xor(v, 1); v += __shfl_xor(v, 2);
    return v;
#endif
}

__device__ __forceinline__ void flag_store(u64* p, u64 v) {
    __hip_atomic_store(p, v, __ATOMIC_RELEASE, __HIP_MEMORY_SCOPE_AGENT);
}
__device__ __forceinline__ u64 flag_load(u64* p) {
    return __hip_atomic_load(p, __ATOMIC_ACQUIRE, __HIP_MEMORY_SCOPE_AGENT);
}
__device__ __forceinline__ void data_store(u32* p, u32 v) {
    __hip_atomic_store(p, v, __ATOMIC_RELAXED, __HIP_MEMORY_SCOPE_AGENT);
}
__device__ __forceinline__ u32 data_load(u32* p) {
    return __hip_atomic_load(p, __ATOMIC_RELAXED, __HIP_MEMORY_SCOPE_AGENT);
}

// -------------------------------------------------------------- sync init ---
__global__ void init_sync_kernel(u64* flags) {
    flags[threadIdx.x] = 0ull;   // 256 enc + 256 dec
}

// ------------------------------------------------------- x-side projections --
__global__ __launch_bounds__(768, 3) void gemm_x_kernel(
    const float* __restrict__ inp, const float* __restrict__ W0,
    const u16* __restrict__ psi16, int mode, int t0, int len, int ct, int nt,
    u16* __restrict__ gout)
{
    const int tid = threadIdx.x;
    const int b = blockIdx.x / nt, tc = blockIdx.x % nt;
    const int gr = tid;
    float w[INP];
    if (mode == 0 || gr < 512) {
        const float* wsrc = W0 + (size_t)gr * INP;
#pragma unroll
        for (int c = 0; c < INP; ++c) w[c] = wsrc[c];
    } else {
        const u16* wsrc = psi16 + (size_t)b * NPSI + OFF_WIH + (size_t)(gr - 512) * INP;
#pragma unroll
        for (int c = 0; c < INP; ++c) w[c] = f16tof(wsrc[c]);
    }
    const int tb = tc * 128;
    const int te = (tb + 128 < len) ? tb + 128 : len;
    for (int tl = tb; tl < te; ++tl) {
        const float* xr = inp + ((size_t)b * TT + t0 + tl) * INP;
        float a = 0.f;
#pragma unroll
        for (int c = 0; c < INP; ++c) a = __builtin_fmaf(xr[c], w[c], a);
        gout[((size_t)b * ct + tl) * 768 + gr] = ftof16(a);
    }
}

// ---------------------------------------------------------------- encoder ---
// 2 blocks per batch (bid&127 = b, bid>>7 = half q). Block q owns outputs
// j in [128q,128q+128): 96 weight-u32/thread -> fits 128 VGPR, no AGPR tax.
// Per-step h-half exchange via L2 (agent atomics + flag).
__global__ __launch_bounds__(512) __attribute__((amdgpu_waves_per_eu(2, 2)))
void enc_scan_kernel(
    const u16* __restrict__ gi, int t0, int len, int ct,
    const float* __restrict__ Whh, const float* __restrict__ bih,
    const float* __restrict__ bhh, float* __restrict__ hcarry,
    u64* __restrict__ flags, u32* __restrict__ hx)
{
    __shared__ __align__(16) u32 hpp[2][144];
    const int tid = threadIdx.x;
    const int b = blockIdx.x & 127, qh = blockIdx.x >> 7;
    const int l = tid & 3, jloc = tid >> 2;
    const int j = 128 * qh + jloc;

    u32 wr[32], wz[32], wn[32];
    {
        const float* pr = Whh + (size_t)j * 256 + 64 * l;
        const float* pz = Whh + (size_t)(256 + j) * 256 + 64 * l;
        const float* pn = Whh + (size_t)(512 + j) * 256 + 64 * l;
#pragma unroll
        for (int c = 0; c < 32; ++c) {
            wr[c] = pk(pr[2 * c], pr[2 * c + 1]);
            wz[c] = pk(pz[2 * c], pz[2 * c + 1]);
            wn[c] = pk(pn[2 * c], pn[2 * c + 1]);
        }
    }
    const float brb = bih[j] + bhh[j];
    const float bzb = bih[256 + j] + bhh[256 + j];
    const float bib = bih[512 + j];
    const float bhb = bhh[512 + j];
    float hc = 0.f;
    if (t0 > 0) hc = hcarry[(size_t)b * 256 + j];
    if (tid < 128) {
        u32 hv = 0u;
        if (t0 > 0) hv = pk(hcarry[(size_t)b * 256 + 2 * tid], hcarry[(size_t)b * 256 + 2 * tid + 1]);
        hpp[0][36 * (tid >> 5) + (tid & 31)] = hv;
    }
    __syncthreads();

    const u16* gbase = gi + (size_t)b * ct * 768;
    u16 c0 = gbase[j], c1 = gbase[256 + j], c2 = gbase[512 + j];
    u64* fown = flags + (b * 2 + qh);
    u64* fpar = flags + (b * 2 + (qh ^ 1));
    u32* hxo = hx + (size_t)(b * 2 + qh) * 64;
    u32* hxp = hx + (size_t)(b * 2 + (qh ^ 1)) * 64;

    for (int tl = 0; tl < len; ++tl) {
        const int p = tl & 1;
        u16 n0 = 0, n1 = 0, n2 = 0;
        if (tl + 1 < len) {
            const u16* gn = gbase + (size_t)(tl + 1) * 768;
            n0 = gn[j]; n1 = gn[256 + j]; n2 = gn[512 + j];
        }
        float ar = 0, az = 0, ah = 0;
        const uint4* hq = (const uint4*)hpp[p];
#pragma unroll
        for (int cc = 0; cc < 8; ++cc) {
            uint4 q4 = hq[9 * l + cc];
            u32 qa[4] = {q4.x, q4.y, q4.z, q4.w};
#pragma unroll
            for (int u = 0; u < 4; ++u) {
                const int c = cc * 4 + u;
                ar = fd2(wr[c], qa[u], ar);
                az = fd2(wz[c], qa[u], az);
                ah = fd2(wn[c], qa[u], ah);
            }
        }
        ar = qred(ar); az = qred(az); ah = qred(ah);
        {
            float r = fsig(ar + f16tof(c0) + brb);
            float z = fsig(az + f16tof(c1) + bzb);
            float nn = ftanh(f16tof(c2) + bib + r * (ah + bhb));
            float hn = (1.f - z) * nn + z * hc;
            hc = hn;
            float ho = __shfl_xor(hn, 4);
            if (l == 0 && !(jloc & 1)) {
                const int lp = jloc >> 1;
                const int gp = 64 * qh + lp;
                u32 hv = pk(hn, ho);
                hpp[p ^ 1][36 * (gp >> 5) + (gp & 31)] = hv;
                data_store(&hxo[lp], hv);
            }
        }
        __syncthreads();
        if (tid == 0) flag_store(fown, (u64)(t0 + tl + 1));
        const u64 tgt = (u64)(t0 + tl + 1);
        while (flag_load(fpar) < tgt) __builtin_amdgcn_s_sleep(1);
        if (tid < 64) {
            u32 v = data_load(&hxp[tid]);
            const int gp = 64 * (qh ^ 1) + tid;
            hpp[p ^ 1][36 * (gp >> 5) + (gp & 31)] = v;
        }
        c0 = n0; c1 = n1; c2 = n2;
        __syncthreads();
    }
    if (l == 0) hcarry[(size_t)b * 256 + j] = hc;
}

// ----------------------------------------------------------------- latent ---
__global__ __launch_bounds__(256) void latent_kernel(
    const float* __restrict__ henc, const float* __restrict__ eps,
    const float* __restrict__ to_mu, const float* __restrict__ to_ls,
    const float* __restrict__ W1, const float* __restrict__ b1,
    const float* __restrict__ W2, const float* __restrict__ b2,
    float* __restrict__ psi2, float* __restrict__ out)
{
    __shared__ float h[256], zz[16], p1[256];
    const int tid = threadIdx.x, b = blockIdx.x;
    h[tid] = henc[(size_t)b * 256 + tid];
    __syncthreads();
    if (tid < 16) {
        float m = 0, s = 0;
        for (int k = 0; k < 256; ++k) {
            m += h[k] * to_mu[tid * 256 + k];
            s += h[k] * to_ls[tid * 256 + k];
        }
        out[OUT_MU + b * 16 + tid] = m;
        out[OUT_LS + b * 16 + tid] = s;
        zz[tid] = m + eps[b * 16 + tid] * __expf(s);
    }
    __syncthreads();
    {
        float a = b1[tid];
        for (int k = 0; k < 16; ++k) a += zz[k] * W1[tid * 16 + k];
        p1[tid] = ftanh(a);
    }
    __syncthreads();
    if (tid < 32) {
        float a = b2[tid];
        for (int k = 0; k < 256; ++k) a += p1[k] * W2[tid * 256 + k];
        psi2[b * 32 + tid] = a;
    }
}

// ------------------------------------------------------------------- psi3 ---
__global__ __launch_bounds__(256) void psi3_kernel(
    const float* __restrict__ psi2, const float* __restrict__ W3,
    const float* __restrict__ b3, u16* __restrict__ psi16)
{
    __shared__ float sp2[128 * 32];
    __shared__ float w3t[256 * 33];
    const int tid = threadIdx.x;
    const int n0 = blockIdx.x * 256;
    for (int idx = tid; idx < 4096; idx += 256) sp2[idx] = psi2[idx];
    for (int idx = tid; idx < 8192; idx += 256) {
        int row = idx >> 5, k = idx & 31;
        int n = n0 + row;
        w3t[row * 33 + k] = (n < NPSI) ? W3[(size_t)n * 32 + k] : 0.f;
    }
    __syncthreads();
    const int n = n0 + tid;
    if (n < NPSI) {
        float w[32];
#pragma unroll
        for (int k = 0; k < 32; ++k) w[k] = w3t[tid * 33 + k];
        const float bv = b3[n];
        for (int bi = 0; bi < 128; ++bi) {
            float a = bv;
#pragma unroll
            for (int k = 0; k < 32; ++k) a += sp2[bi * 32 + k] * w[k];
            psi16[(size_t)bi * NPSI + n] = ftof16(a);
        }
    }
}

// --------------------------- decoder scan (split) + fused C_p half-einsum ---
__global__ __launch_bounds__(512) __attribute__((amdgpu_waves_per_eu(2, 2)))
void dec_scan_kernel(
    const u16* __restrict__ gx, int t0, int len, int ct,
    const float* __restrict__ state, const float* __restrict__ gWhh,
    const float* __restrict__ gbias, const u16* __restrict__ psi16,
    float* __restrict__ dcarry, float* __restrict__ out,
    u64* __restrict__ flags, u32* __restrict__ hx)
{
    __shared__ __align__(16) u32 hpp[2][144];
    __shared__ u32 cp[32 * 129];       // own 32 output cols x 128 pairs
    __shared__ float part[2][16 * 32];
    const int tid = threadIdx.x;
    const int b = blockIdx.x & 127, qh = blockIdx.x >> 7;
    const int l = tid & 3, jloc = tid >> 2;
    const int j = 128 * qh + jloc;
    const u16* pc = psi16 + (size_t)b * NPSI;

    u32 wz[32], wrr[32], wp[32];
#pragma unroll
    for (int c = 0; c < 32; ++c) {
        const int h0 = 64 * l + 2 * c;
        wz[c]  = pk(gWhh[(size_t)h0 * 512 + j], gWhh[(size_t)(h0 + 1) * 512 + j]);
        wrr[c] = pk(gWhh[(size_t)h0 * 512 + 256 + j], gWhh[(size_t)(h0 + 1) * 512 + 256 + j]);
        wp[c]  = (u32)pc[(size_t)h0 * 256 + j] | ((u32)pc[(size_t)(h0 + 1) * 256 + j] << 16);
    }
    const float gzb = gbias[j];
    const float grb = gbias[256 + j];
    const float bhb = f16tof(pc[OFF_BH + j]);
    // C_p columns [32qh, 32qh+32): cp[o32*129 + pair]
    for (int idx = tid; idx < 4096; idx += 512) {
        const int o32 = idx >> 7, pair = idx & 127;
        const int o = 32 * qh + o32;
        cp[o32 * 129 + pair] = (u32)pc[OFF_C + (size_t)(2 * pair) * 64 + o]
                             | ((u32)pc[OFF_C + (size_t)(2 * pair + 1) * 64 + o] << 16);
    }
    const float* hsrc = (t0 == 0) ? state : dcarry;
    float hc = hsrc[(size_t)b * 256 + j];
    if (tid < 128) hpp[0][36 * (tid >> 5) + (tid & 31)] =
        pk(hsrc[(size_t)b * 256 + 2 * tid], hsrc[(size_t)b * 256 + 2 * tid + 1]);
    __syncthreads();

    const u16* gbase = gx + (size_t)b * ct * 768;
    const int o32 = tid & 31, s = tid >> 5;        // yhat: 16 slices x 8 pairs
    const int hqi4 = 9 * (s >> 2) + 2 * (s & 3);   // uint4 idx of pair 8s
    u16 c0 = gbase[j], c1 = gbase[256 + j], c2 = gbase[512 + j];
    u64* fown = flags + (b * 2 + qh);
    u64* fpar = flags + (b * 2 + (qh ^ 1));
    u32* hxo = hx + (size_t)(b * 2 + qh) * 64;
    u32* hxp = hx + (size_t)(b * 2 + (qh ^ 1)) * 64;

    for (int tl = 0; tl < len; ++tl) {
        const int p = tl & 1;
        u16 n0 = 0, n1 = 0, n2 = 0;
        if (tl + 1 < len) {
            const u16* gn = gbase + (size_t)(tl + 1) * 768;
            n0 = gn[j]; n1 = gn[256 + j]; n2 = gn[512 + j];
        }
        // recurrent matvec for own rows
        float az = 0, ar = 0, ap = 0;
        const uint4* hq = (const uint4*)hpp[p];
#pragma unroll
        for (int cc = 0; cc < 8; ++cc) {
            uint4 q4 = hq[9 * l + cc];
            u32 qa[4] = {q4.x, q4.y, q4.z, q4.w};
#pragma unroll
            for (int u = 0; u < 4; ++u) {
                const int c = cc * 4 + u;
                az = fd2(wz[c], qa[u], az);
                ar = fd2(wrr[c], qa[u], ar);
                ap = fd2(wp[c], qa[u], ap);
            }
        }
        az = qred(az); ar = qred(ar); ap = qred(ap);
        {
            float zt = fsig(az + f16tof(c0) + gzb);
            float rt = fsig(ar + f16tof(c1) + grb);
            float eta = ftanh(f16tof(c2) + rt * ftanh(ap + bhb));
            float hn = zt * hc + (1.f - zt) * eta;
            hc = hn;
            float ho = __shfl_xor(hn, 4);
            if (l == 0 && !(jloc & 1)) {
                const int lp = jloc >> 1;
                const int gp = 64 * qh + lp;
                u32 hv = pk(hn, ho);
                hpp[p ^ 1][36 * (gp >> 5) + (gp & 31)] = hv;
                data_store(&hxo[lp], hv);
            }
        }
        __syncthreads();
        if (tid == 0) flag_store(fown, (u64)(t0 + tl + 1));
        // yhat partials for h_{t0+tl-1} (hpp[p], fully assembled) while partner works
        {
            const uint4* h2q = (const uint4*)hpp[p] + hqi4;
            uint4 qa = h2q[0], qb = h2q[1];
            u32 hv[8] = {qa.x, qa.y, qa.z, qa.w, qb.x, qb.y, qb.z, qb.w};
            const int cbase = o32 * 129 + 8 * s;
            float p0 = 0.f, p1 = 0.f;
#pragma unroll
            for (int i = 0; i < 4; ++i) {
                p0 = fd2(hv[2 * i], cp[cbase + 2 * i], p0);
                p1 = fd2(hv[2 * i + 1], cp[cbase + 2 * i + 1], p1);
            }
            part[p][s * 32 + o32] = p0 + p1;
        }
        if (tid < 32 && tl >= 2) {
            float y = 0.f;
#pragma unroll
            for (int s2 = 0; s2 < 16; ++s2) y += part[p ^ 1][s2 * 32 + tid];
            out[((size_t)b * TT + t0 + tl - 2) * HUM + 32 * qh + tid] = y;
        }
        const u64 tgt = (u64)(t0 + tl + 1);
        while (flag_load(fpar) < tgt) __builtin_amdgcn_s_sleep(1);
        if (tid < 64) {
            u32 v = data_load(&hxp[tid]);
            const int gp = 64 * (qh ^ 1) + tid;
            hpp[p ^ 1][36 * (gp >> 5) + (gp & 31)] = v;
        }
        c0 = n0; c1 = n1; c2 = n2;
        __syncthreads();
    }
    // tail: y_{t0+len-2}, then partial+reduce for y_{t0+len-1}
    {
        const int pf = (len - 1) & 1;
        if (tid < 32 && len >= 2) {
            float y = 0.f;
#pragma unroll
            for (int s2 = 0; s2 < 16; ++s2) y += part[pf][s2 * 32 + tid];
            out[((size_t)b * TT + t0 + len - 2) * HUM + 32 * qh + tid] = y;
        }
        const int pl = len & 1;
        {
            const uint4* h2q = (const uint4*)hpp[pl] + hqi4;
            uint4 qa = h2q[0], qb = h2q[1];
            u32 hv[8] = {qa.x, qa.y, qa.z, qa.w, qb.x, qb.y, qb.z, qb.w};
            const int cbase = o32 * 129 + 8 * s;
            float p0 = 0.f, p1 = 0.f;
#pragma unroll
            for (int i = 0; i < 4; ++i) {
                p0 = fd2(hv[2 * i], cp[cbase + 2 * i], p0);
                p1 = fd2(hv[2 * i + 1], cp[cbase + 2 * i + 1], p1);
            }
            part[pl][s * 32 + o32] = p0 + p1;
        }
        __syncthreads();
        if (tid < 32) {
            float y = 0.f;
#pragma unroll
            for (int s2 = 0; s2 < 16; ++s2) y += part[pl][s2 * 32 + tid];
            out[((size_t)b * TT + t0 + len - 1) * HUM + 32 * qh + tid] = y;
        }
    }
    if (l == 0) {
        dcarry[(size_t)b * 256 + j] = hc;
        if (t0 + len == TT) out[OUT_HL + (size_t)b * 256 + j] = hc;
    }
}

// ------------------------------------------------- x add + D_p einsum fixup --
__global__ __launch_bounds__(256) void post_kernel(
    const float* __restrict__ inp, const u16* __restrict__ psi16,
    float* __restrict__ out)
{
    __shared__ float xs[128][55];
    __shared__ float ds[INP][10];
    const int tid = threadIdx.x;
    const int b = blockIdx.x >> 3, tile = blockIdx.x & 7;
    const int t0 = tile * 128;
    const u16* pc = psi16 + (size_t)b * NPSI;
    for (int idx = tid; idx < 540; idx += 256)
        ds[idx / 10][idx % 10] = f16tof(pc[OFF_D + idx]);
    for (int idx = tid; idx < 128 * INP; idx += 256) {
        const int t = idx / INP, d = idx % INP;
        xs[t][d] = inp[((size_t)b * TT + t0 + t) * INP + d];
    }
    __syncthreads();
    for (int i = 0; i < 32; ++i) {
        const int flat = i * 256 + tid;
        const int t = flat >> 6, o = flat & 63;
        const size_t oi = ((size_t)b * TT + t0 + t) * HUM + o;
        float y = out[oi];
        if (o < INP) y += xs[t][o];
        else {
            float acc = 0.f;
            for (int d = 0; d < INP; ++d) acc += xs[t][d] * ds[d][o - INP];
            y += acc;
        }
        out[oi] = y;
    }
}

// ----------------------------------------------------------------- launch ---
extern "C" void kernel_launch(void* const* d_in, const int* in_sizes, int n_in,
                              void* d_out, int out_size, void* d_ws, size_t ws_size,
                              hipStream_t stream)
{
    const float* inputs = (const float*)d_in[0];
    const float* state  = (const float*)d_in[1];
    const float* eps    = (const float*)d_in[2];
    const float* eWih   = (const float*)d_in[3];
    const float* eWhh   = (const float*)d_in[4];
    const float* ebih   = (const float*)d_in[5];
    const float* ebhh   = (const float*)d_in[6];
    const float* to_mu  = (const float*)d_in[7];
    const float* to_ls  = (const float*)d_in[8];
    const float* W1     = (const float*)d_in[9];
    const float* b1     = (const float*)d_in[10];
    const float* W2     = (const float*)d_in[11];
    const float* b2     = (const float*)d_in[12];
    const float* W3     = (const float*)d_in[13];
    const float* b3     = (const float*)d_in[14];
    const float* gWih   = (const float*)d_in[15];
    const float* gWhh   = (const float*)d_in[16];
    const float* gbias  = (const float*)d_in[17];
    float* out = (float*)d_out;
    float* ws  = (float*)d_ws;

    float* henc   = ws;                              // 32768
    float* psi2   = ws + 32768;                      // 4096
    float* dcarry = ws + 36864;                      // 32768
    u16*   psi16  = (u16*)(ws + 69632);              // 24,714,240 B
    u64*   flags  = (u64*)(ws + 6248192);            // 512 u64 (256 enc + 256 dec)
    u32*   hx     = (u32*)(ws + 6249216);            // 16384 u32
    u16*   gbuf   = (u16*)(ws + 6265600);
    const size_t used = (size_t)6265600 * 4;
    size_t avail = (ws_size > used + 4096) ? (ws_size - used - 4096) : 0;
    int ct = (int)(avail / ((size_t)BB * 768 * 2));
    if (ct > TT) ct = TT;
    if (ct < 1) ct = 1;

    init_sync_kernel<<<1, 512, 0, stream>>>(flags);

    for (int t0 = 0; t0 < TT; t0 += ct) {
        const int len = (TT - t0 < ct) ? (TT - t0) : ct;
        const int nt = (len + 127) / 128;
        gemm_x_kernel<<<BB * nt, 768, 0, stream>>>(inputs, eWih, psi16, 0, t0, len, ct, nt, gbuf);
        enc_scan_kernel<<<256, 512, 0, stream>>>(gbuf, t0, len, ct, eWhh, ebih, ebhh, henc,
                                                 flags, hx);
    }
    latent_kernel<<<BB, 256, 0, stream>>>(henc, eps, to_mu, to_ls, W1, b1, W2, b2, psi2, out);
    psi3_kernel<<<(NPSI + 255) / 256, 256, 0, stream>>>(psi2, W3, b3, psi16);
    for (int t0 = 0; t0 < TT; t0 += ct) {
        const int len = (TT - t0 < ct) ? (TT - t0) : ct;
        const int nt = (len + 127) / 128;
        gemm_x_kernel<<<BB * nt, 768, 0, stream>>>(inputs, gWih, psi16, 1, t0, len, ct, nt, gbuf);
        dec_scan_kernel<<<256, 512, 0, stream>>>(gbuf, t0, len, ct, state, gWhh, gbias, psi16,
                                                 dcarry, out, flags + 256, hx);
    }
    post_kernel<<<BB * 8, 256, 0, stream>>>(inputs, psi16, out);
}

// Round 11
// 4706.409 us; speedup vs baseline: 11.7751x; 11.7751x over previous
//
#include <hip/hip_runtime.h>

#define BB 128
#define TT 1024
#define INP 54
#define HUM 64
#define NPSI 96540
#define OFF_BH 65536
#define OFF_WIH 65792
#define OFF_C 79616
#define OFF_D 96000
#define OUT_MU 8388608
#define OUT_LS 8390656
#define OUT_HL 8392704

typedef unsigned int u32;
typedef unsigned short u16;
typedef _Float16 h2 __attribute__((ext_vector_type(2)));

__device__ __forceinline__ u32 pk(float a, float b) {
    h2 v; v.x = (_Float16)a; v.y = (_Float16)b;
    return __builtin_bit_cast(u32, v);
}
__device__ __forceinline__ float f16tof(u16 v) {
    return (float)__builtin_bit_cast(_Float16, v);
}
__device__ __forceinline__ u16 ftof16(float v) {
    return __builtin_bit_cast(u16, (_Float16)v);
}
__device__ __forceinline__ float lo16f(u32 v) { return f16tof((u16)(v & 0xffffu)); }
__device__ __forceinline__ float hi16f(u32 v) { return f16tof((u16)(v >> 16)); }
__device__ __forceinline__ h2 bch2(u32 a) { return __builtin_bit_cast(h2, a); }
__device__ __forceinline__ float fd2(u32 a, u32 b, float c) {
#if __has_builtin(__builtin_amdgcn_fdot2)
    return __builtin_amdgcn_fdot2(bch2(a), bch2(b), c, false);
#else
    return c + lo16f(a) * lo16f(b) + hi16f(a) * hi16f(b);
#endif
}
// packed f16 fma: 2 MACs/inst
__device__ __forceinline__ h2 pfma(u32 a, u32 b, h2 c) {
    return bch2(a) * bch2(b) + c;
}
__device__ __forceinline__ float h2tof(h2 s) { return (float)s.x + (float)s.y; }
__device__ __forceinline__ float fsig(float x) { return 1.f / (1.f + __expf(-x)); }
__device__ __forceinline__ float ftanh(float x) { float e = __expf(2.f * x); return 1.f - 2.f / (e + 1.f); }

__device__ __forceinline__ float qred(float v) {
#if __has_builtin(__builtin_amdgcn_mov_dpp)
    int x = __builtin_bit_cast(int, v);
    v += __builtin_bit_cast(float, __builtin_amdgcn_mov_dpp(x, 0xB1, 0xF, 0xF, true)); // [1,0,3,2]
    x = __builtin_bit_cast(int, v);
    v += __builtin_bit_cast(float, __builtin_amdgcn_mov_dpp(x, 0x4E, 0xF, 0xF, true)); // [2,3,0,1]
    return v;
#else
    v += __shfl_xor(v, 1); v += __shfl_xor(v, 2);
    return v;
#endif
}

// ------------------------------------------------------- x-side projections --
__global__ __launch_bounds__(768, 3) void gemm_x_kernel(
    const float* __restrict__ inp, const float* __restrict__ W0,
    const u16* __restrict__ psi16, int mode, int t0, int len, int ct, int nt,
    u16* __restrict__ gout)
{
    const int tid = threadIdx.x;
    const int b = blockIdx.x / nt, tc = blockIdx.x % nt;
    const int gr = tid;
    float w[INP];
    if (mode == 0 || gr < 512) {
        const float* wsrc = W0 + (size_t)gr * INP;
#pragma unroll
        for (int c = 0; c < INP; ++c) w[c] = wsrc[c];
    } else {
        const u16* wsrc = psi16 + (size_t)b * NPSI + OFF_WIH + (size_t)(gr - 512) * INP;
#pragma unroll
        for (int c = 0; c < INP; ++c) w[c] = f16tof(wsrc[c]);
    }
    const int tb = tc * 128;
    const int te = (tb + 128 < len) ? tb + 128 : len;
    for (int tl = tb; tl < te; ++tl) {
        const float* xr = inp + ((size_t)b * TT + t0 + tl) * INP;
        float a = 0.f;
#pragma unroll
        for (int c = 0; c < INP; ++c) a = __builtin_fmaf(xr[c], w[c], a);
        gout[((size_t)b * ct + tl) * 768 + gr] = ftof16(a);
    }
}

// ---------------------------------------------------------------- encoder ---
// r8 geometry (512 thr, 2 rows/thread, quad K-split) + LDS-staged gx
// (8-step double buffer) + pk_fma matvec (A/B test vs dec's dot2).
__global__ __launch_bounds__(512) __attribute__((amdgpu_waves_per_eu(2, 2)))
void enc_scan_kernel(
    const u16* __restrict__ gi, int t0, int len, int ct,
    const float* __restrict__ Whh, const float* __restrict__ bih,
    const float* __restrict__ bhh, float* __restrict__ hcarry)
{
    __shared__ __align__(16) u32 hpp[2][144];
    __shared__ __align__(16) u32 gxs[2][3072];     // 8 steps x 384 u32
    const int tid = threadIdx.x, b = blockIdx.x;
    const int l = tid & 3, g = tid >> 2;
    const int j0 = 2 * g, j1 = 2 * g + 1;

    u32 wr0[32], wz0[32], wn0[32], wr1[32], wz1[32], wn1[32];
    {
        const float* pr0 = Whh + (size_t)j0 * 256 + 64 * l;
        const float* pz0 = Whh + (size_t)(256 + j0) * 256 + 64 * l;
        const float* pn0 = Whh + (size_t)(512 + j0) * 256 + 64 * l;
        const float* pr1 = Whh + (size_t)j1 * 256 + 64 * l;
        const float* pz1 = Whh + (size_t)(256 + j1) * 256 + 64 * l;
        const float* pn1 = Whh + (size_t)(512 + j1) * 256 + 64 * l;
#pragma unroll
        for (int c = 0; c < 32; ++c) {
            wr0[c] = pk(pr0[2 * c], pr0[2 * c + 1]);
            wz0[c] = pk(pz0[2 * c], pz0[2 * c + 1]);
            wn0[c] = pk(pn0[2 * c], pn0[2 * c + 1]);
            wr1[c] = pk(pr1[2 * c], pr1[2 * c + 1]);
            wz1[c] = pk(pz1[2 * c], pz1[2 * c + 1]);
            wn1[c] = pk(pn1[2 * c], pn1[2 * c + 1]);
        }
    }
    const float brb0 = bih[j0] + bhh[j0],             brb1 = bih[j1] + bhh[j1];
    const float bzb0 = bih[256 + j0] + bhh[256 + j0], bzb1 = bih[256 + j1] + bhh[256 + j1];
    const float bib0 = bih[512 + j0],                 bib1 = bih[512 + j1];
    const float bhb0 = bhh[512 + j0],                 bhb1 = bhh[512 + j1];
    float hc0 = 0.f, hc1 = 0.f;
    if (t0 > 0) { hc0 = hcarry[(size_t)b * 256 + j0]; hc1 = hcarry[(size_t)b * 256 + j1]; }
    if (tid < 128) {
        u32 hv = 0u;
        if (t0 > 0) hv = pk(hcarry[(size_t)b * 256 + 2 * tid], hcarry[(size_t)b * 256 + 2 * tid + 1]);
        hpp[0][36 * (tid >> 5) + (tid & 31)] = hv;
    }
    const u32* gb32 = (const u32*)(gi + (size_t)b * ct * 768);
    {
        const int steps0 = (len < 8) ? len : 8;
#pragma unroll
        for (int k = 0; k < 6; ++k) {
            const int f = k * 512 + tid;
            if (f < 384 * steps0) gxs[0][f] = gb32[f];
        }
    }
    __syncthreads();

    const h2 z2 = {(_Float16)0.f, (_Float16)0.f};
    int buf = 0;
    for (int cb = 0; cb < len; cb += 8) {
        const int steps = (len - cb < 8) ? (len - cb) : 8;
        const int nsteps = (len - cb - 8 < 8) ? (len - cb - 8) : 8;
        u32 stg[6];
        if (nsteps > 0) {
            const u32* gsrc = gb32 + (size_t)(cb + 8) * 384;
#pragma unroll
            for (int k = 0; k < 6; ++k) {
                const int f = k * 512 + tid;
                if (f < 384 * nsteps) stg[k] = gsrc[f];
            }
        }
        for (int st = 0; st < steps; ++st) {
            const int tl = cb + st;
            const int p = tl & 1;
            const u32 c0 = gxs[buf][st * 384 + g];
            const u32 c1 = gxs[buf][st * 384 + 128 + g];
            const u32 c2 = gxs[buf][st * 384 + 256 + g];
            h2 vr0a = z2, vr0b = z2, vz0a = z2, vz0b = z2, vn0a = z2, vn0b = z2;
            h2 vr1a = z2, vr1b = z2, vz1a = z2, vz1b = z2, vn1a = z2, vn1b = z2;
            const uint4* hq = (const uint4*)hpp[p];
#pragma unroll
            for (int cc = 0; cc < 8; ++cc) {
                uint4 q = hq[9 * l + cc];
                u32 qa[4] = {q.x, q.y, q.z, q.w};
#pragma unroll
                for (int u = 0; u < 4; ++u) {
                    const int c = cc * 4 + u;
                    if (u & 1) {
                        vr0b = pfma(wr0[c], qa[u], vr0b);
                        vz0b = pfma(wz0[c], qa[u], vz0b);
                        vn0b = pfma(wn0[c], qa[u], vn0b);
                        vr1b = pfma(wr1[c], qa[u], vr1b);
                        vz1b = pfma(wz1[c], qa[u], vz1b);
                        vn1b = pfma(wn1[c], qa[u], vn1b);
                    } else {
                        vr0a = pfma(wr0[c], qa[u], vr0a);
                        vz0a = pfma(wz0[c], qa[u], vz0a);
                        vn0a = pfma(wn0[c], qa[u], vn0a);
                        vr1a = pfma(wr1[c], qa[u], vr1a);
                        vz1a = pfma(wz1[c], qa[u], vz1a);
                        vn1a = pfma(wn1[c], qa[u], vn1a);
                    }
                }
            }
            float ar0 = qred(h2tof(vr0a + vr0b));
            float az0 = qred(h2tof(vz0a + vz0b));
            float ah0 = qred(h2tof(vn0a + vn0b));
            float ar1 = qred(h2tof(vr1a + vr1b));
            float az1 = qred(h2tof(vz1a + vz1b));
            float ah1 = qred(h2tof(vn1a + vn1b));
            {
                float r0 = fsig(ar0 + lo16f(c0) + brb0);
                float z0 = fsig(az0 + lo16f(c1) + bzb0);
                float nn0 = ftanh(lo16f(c2) + bib0 + r0 * (ah0 + bhb0));
                float hn0 = (1.f - z0) * nn0 + z0 * hc0;
                float r1 = fsig(ar1 + hi16f(c0) + brb1);
                float z1 = fsig(az1 + hi16f(c1) + bzb1);
                float nn1 = ftanh(hi16f(c2) + bib1 + r1 * (ah1 + bhb1));
                float hn1 = (1.f - z1) * nn1 + z1 * hc1;
                hc0 = hn0; hc1 = hn1;
                if (l == 0) hpp[p ^ 1][36 * (g >> 5) + (g & 31)] = pk(hn0, hn1);
            }
            __syncthreads();
        }
        if (nsteps > 0) {
#pragma unroll
            for (int k = 0; k < 6; ++k) {
                const int f = k * 512 + tid;
                if (f < 384 * nsteps) gxs[buf ^ 1][f] = stg[k];
            }
        }
        __syncthreads();
        buf ^= 1;
    }
    if (l == 0) {
        hcarry[(size_t)b * 256 + j0] = hc0;
        hcarry[(size_t)b * 256 + j1] = hc1;
    }
}

// ----------------------------------------------------------------- latent ---
__global__ __launch_bounds__(256) void latent_kernel(
    const float* __restrict__ henc, const float* __restrict__ eps,
    const float* __restrict__ to_mu, const float* __restrict__ to_ls,
    const float* __restrict__ W1, const float* __restrict__ b1,
    const float* __restrict__ W2, const float* __restrict__ b2,
    float* __restrict__ psi2, float* __restrict__ out)
{
    __shared__ float h[256], zz[16], p1[256];
    const int tid = threadIdx.x, b = blockIdx.x;
    h[tid] = henc[(size_t)b * 256 + tid];
    __syncthreads();
    if (tid < 16) {
        float m = 0, s = 0;
        for (int k = 0; k < 256; ++k) {
            m += h[k] * to_mu[tid * 256 + k];
            s += h[k] * to_ls[tid * 256 + k];
        }
        out[OUT_MU + b * 16 + tid] = m;
        out[OUT_LS + b * 16 + tid] = s;
        zz[tid] = m + eps[b * 16 + tid] * __expf(s);
    }
    __syncthreads();
    {
        float a = b1[tid];
        for (int k = 0; k < 16; ++k) a += zz[k] * W1[tid * 16 + k];
        p1[tid] = ftanh(a);
    }
    __syncthreads();
    if (tid < 32) {
        float a = b2[tid];
        for (int k = 0; k < 256; ++k) a += p1[k] * W2[tid * 256 + k];
        psi2[b * 32 + tid] = a;
    }
}

// ------------------------------------------------------------------- psi3 ---
__global__ __launch_bounds__(256) void psi3_kernel(
    const float* __restrict__ psi2, const float* __restrict__ W3,
    const float* __restrict__ b3, u16* __restrict__ psi16)
{
    __shared__ float sp2[128 * 32];
    __shared__ float w3t[256 * 33];
    const int tid = threadIdx.x;
    const int n0 = blockIdx.x * 256;
    for (int idx = tid; idx < 4096; idx += 256) sp2[idx] = psi2[idx];
    for (int idx = tid; idx < 8192; idx += 256) {
        int row = idx >> 5, k = idx & 31;
        int n = n0 + row;
        w3t[row * 33 + k] = (n < NPSI) ? W3[(size_t)n * 32 + k] : 0.f;
    }
    __syncthreads();
    const int n = n0 + tid;
    if (n < NPSI) {
        float w[32];
#pragma unroll
        for (int k = 0; k < 32; ++k) w[k] = w3t[tid * 33 + k];
        const float bv = b3[n];
        for (int bi = 0; bi < 128; ++bi) {
            float a = bv;
#pragma unroll
            for (int k = 0; k < 32; ++k) a += sp2[bi * 32 + k] * w[k];
            psi16[(size_t)bi * NPSI + n] = ftof16(a);
        }
    }
}

// ------------------------------- decoder scan (dot2) + hseq trace, no yhat --
__global__ __launch_bounds__(512) __attribute__((amdgpu_waves_per_eu(2, 2)))
void dec_scan_kernel(
    const u16* __restrict__ gx, int t0, int len, int ct,
    const float* __restrict__ state, const float* __restrict__ gWhh,
    const float* __restrict__ gbias, const u16* __restrict__ psi16,
    float* __restrict__ dcarry, u32* __restrict__ hseq, float* __restrict__ out)
{
    __shared__ __align__(16) u32 hpp[2][144];
    __shared__ __align__(16) u32 gxs[2][3072];
    const int tid = threadIdx.x, b = blockIdx.x;
    const int l = tid & 3, g = tid >> 2;
    const int j0 = 2 * g, j1 = 2 * g + 1;
    const u16* pc = psi16 + (size_t)b * NPSI;

    u32 wz0[32], wr0[32], wp0[32], wz1[32], wr1[32], wp1[32];
#pragma unroll
    for (int c = 0; c < 32; ++c) {
        const int h0 = 64 * l + 2 * c;
        wz0[c] = pk(gWhh[(size_t)h0 * 512 + j0], gWhh[(size_t)(h0 + 1) * 512 + j0]);
        wr0[c] = pk(gWhh[(size_t)h0 * 512 + 256 + j0], gWhh[(size_t)(h0 + 1) * 512 + 256 + j0]);
        wp0[c] = (u32)pc[(size_t)h0 * 256 + j0] | ((u32)pc[(size_t)(h0 + 1) * 256 + j0] << 16);
        wz1[c] = pk(gWhh[(size_t)h0 * 512 + j1], gWhh[(size_t)(h0 + 1) * 512 + j1]);
        wr1[c] = pk(gWhh[(size_t)h0 * 512 + 256 + j1], gWhh[(size_t)(h0 + 1) * 512 + 256 + j1]);
        wp1[c] = (u32)pc[(size_t)h0 * 256 + j1] | ((u32)pc[(size_t)(h0 + 1) * 256 + j1] << 16);
    }
    const float gzb0 = gbias[j0], gzb1 = gbias[j1];
    const float grb0 = gbias[256 + j0], grb1 = gbias[256 + j1];
    const float bhb0 = f16tof(pc[OFF_BH + j0]), bhb1 = f16tof(pc[OFF_BH + j1]);
    const float* hsrc = (t0 == 0) ? state : dcarry;
    float hc0 = hsrc[(size_t)b * 256 + j0];
    float hc1 = hsrc[(size_t)b * 256 + j1];
    if (tid < 128) hpp[0][36 * (tid >> 5) + (tid & 31)] =
        pk(hsrc[(size_t)b * 256 + 2 * tid], hsrc[(size_t)b * 256 + 2 * tid + 1]);
    const u32* gb32 = (const u32*)(gx + (size_t)b * ct * 768);
    {
        const int steps0 = (len < 8) ? len : 8;
#pragma unroll
        for (int k = 0; k < 6; ++k) {
            const int f = k * 512 + tid;
            if (f < 384 * steps0) gxs[0][f] = gb32[f];
        }
    }
    __syncthreads();

    u32* hsb = hseq + (size_t)b * TT * 128;
    int buf = 0;
    for (int cb = 0; cb < len; cb += 8) {
        const int steps = (len - cb < 8) ? (len - cb) : 8;
        const int nsteps = (len - cb - 8 < 8) ? (len - cb - 8) : 8;
        u32 stg[6];
        if (nsteps > 0) {
            const u32* gsrc = gb32 + (size_t)(cb + 8) * 384;
#pragma unroll
            for (int k = 0; k < 6; ++k) {
                const int f = k * 512 + tid;
                if (f < 384 * nsteps) stg[k] = gsrc[f];
            }
        }
        for (int st = 0; st < steps; ++st) {
            const int tl = cb + st;
            const int p = tl & 1;
            const u32 c0 = gxs[buf][st * 384 + g];
            const u32 c1 = gxs[buf][st * 384 + 128 + g];
            const u32 c2 = gxs[buf][st * 384 + 256 + g];
            float az0 = 0, ar0 = 0, ap0 = 0, az1 = 0, ar1 = 0, ap1 = 0;
            const uint4* hq = (const uint4*)hpp[p];
#pragma unroll
            for (int cc = 0; cc < 8; ++cc) {
                uint4 q = hq[9 * l + cc];
                u32 qa[4] = {q.x, q.y, q.z, q.w};
#pragma unroll
                for (int u = 0; u < 4; ++u) {
                    const int c = cc * 4 + u;
                    az0 = fd2(wz0[c], qa[u], az0);
                    ar0 = fd2(wr0[c], qa[u], ar0);
                    ap0 = fd2(wp0[c], qa[u], ap0);
                    az1 = fd2(wz1[c], qa[u], az1);
                    ar1 = fd2(wr1[c], qa[u], ar1);
                    ap1 = fd2(wp1[c], qa[u], ap1);
                }
            }
            az0 = qred(az0); ar0 = qred(ar0); ap0 = qred(ap0);
            az1 = qred(az1); ar1 = qred(ar1); ap1 = qred(ap1);
            {
                float zt0 = fsig(az0 + lo16f(c0) + gzb0);
                float rt0 = fsig(ar0 + lo16f(c1) + grb0);
                float eta0 = ftanh(lo16f(c2) + rt0 * ftanh(ap0 + bhb0));
                float hn0 = zt0 * hc0 + (1.f - zt0) * eta0;
                float zt1 = fsig(az1 + hi16f(c0) + gzb1);
                float rt1 = fsig(ar1 + hi16f(c1) + grb1);
                float eta1 = ftanh(hi16f(c2) + rt1 * ftanh(ap1 + bhb1));
                float hn1 = zt1 * hc1 + (1.f - zt1) * eta1;
                hc0 = hn0; hc1 = hn1;
                if (l == 0) {
                    u32 hv = pk(hn0, hn1);
                    hpp[p ^ 1][36 * (g >> 5) + (g & 31)] = hv;
                    hsb[(size_t)(t0 + tl) * 128 + g] = hv;
                }
            }
            __syncthreads();
        }
        if (nsteps > 0) {
#pragma unroll
            for (int k = 0; k < 6; ++k) {
                const int f = k * 512 + tid;
                if (f < 384 * nsteps) gxs[buf ^ 1][f] = stg[k];
            }
        }
        __syncthreads();
        buf ^= 1;
    }
    if (l == 0) {
        dcarry[(size_t)b * 256 + j0] = hc0;
        dcarry[(size_t)b * 256 + j1] = hc1;
        if (t0 + len == TT) {
            out[OUT_HL + (size_t)b * 256 + j0] = hc0;
            out[OUT_HL + (size_t)b * 256 + j1] = hc1;
        }
    }
}

// ------------------------------------------------------------------- yhat ---
// y[b,t,o] = sum_h hseq[b][t][h-pair] . C_p[pair][o]  (r1-proven structure)
#define YT 32
__global__ __launch_bounds__(256) void yhat_kernel(
    const u32* __restrict__ hseq, const u16* __restrict__ psi16,
    float* __restrict__ out)
{
    __shared__ float part[2][YT][64];
    const int tid = threadIdx.x;
    const int b = blockIdx.x >> 5, tile = blockIdx.x & 31;
    const int o = tid & 63, s = (tid >> 6) & 1, tq = tid >> 7;
    const u16* pc = psi16 + (size_t)b * NPSI;
    u32 cpr[64];
#pragma unroll
    for (int i = 0; i < 64; ++i) {
        const int gp = s * 64 + i;
        cpr[i] = (u32)pc[OFF_C + (size_t)(2 * gp) * 64 + o]
               | ((u32)pc[OFF_C + (size_t)(2 * gp + 1) * 64 + o] << 16);
    }
    const int t0 = tile * YT;
    for (int th = 0; th < YT / 2; ++th) {
        const int tl = tq * (YT / 2) + th;
        const uint4* h4 = (const uint4*)(hseq + ((size_t)b * TT + t0 + tl) * 128 + s * 64);
        float a = 0.f;
#pragma unroll
        for (int gc = 0; gc < 16; ++gc) {
            uint4 q = h4[gc];
            a = fd2(q.x, cpr[gc * 4 + 0], a);
            a = fd2(q.y, cpr[gc * 4 + 1], a);
            a = fd2(q.z, cpr[gc * 4 + 2], a);
            a = fd2(q.w, cpr[gc * 4 + 3], a);
        }
        part[s][tl][o] = a;
    }
    __syncthreads();
    for (int i = 0; i < 8; ++i) {
        const int flat = i * 256 + tid;
        const int tl = flat >> 6, o2 = flat & 63;
        out[((size_t)b * TT + t0 + tl) * HUM + o2] = part[0][tl][o2] + part[1][tl][o2];
    }
}

// ------------------------------------------------- x add + D_p einsum fixup --
__global__ __launch_bounds__(256) void post_kernel(
    const float* __restrict__ inp, const u16* __restrict__ psi16,
    float* __restrict__ out)
{
    __shared__ float xs[128][55];
    __shared__ float ds[INP][10];
    const int tid = threadIdx.x;
    const int b = blockIdx.x >> 3, tile = blockIdx.x & 7;
    const int t0 = tile * 128;
    const u16* pc = psi16 + (size_t)b * NPSI;
    for (int idx = tid; idx < 540; idx += 256)
        ds[idx / 10][idx % 10] = f16tof(pc[OFF_D + idx]);
    for (int idx = tid; idx < 128 * INP; idx += 256) {
        const int t = idx / INP, d = idx % INP;
        xs[t][d] = inp[((size_t)b * TT + t0 + t) * INP + d];
    }
    __syncthreads();
    for (int i = 0; i < 32; ++i) {
        const int flat = i * 256 + tid;
        const int t = flat >> 6, o = flat & 63;
        const size_t oi = ((size_t)b * TT + t0 + t) * HUM + o;
        float y = out[oi];
        if (o < INP) y += xs[t][o];
        else {
            float acc = 0.f;
            for (int d = 0; d < INP; ++d) acc += xs[t][d] * ds[d][o - INP];
            y += acc;
        }
        out[oi] = y;
    }
}

// ----------------------------------------------------------------- launch ---
extern "C" void kernel_launch(void* const* d_in, const int* in_sizes, int n_in,
                              void* d_out, int out_size, void* d_ws, size_t ws_size,
                              hipStream_t stream)
{
    const float* inputs = (const float*)d_in[0];
    const float* state  = (const float*)d_in[1];
    const float* eps    = (const float*)d_in[2];
    const float* eWih   = (const float*)d_in[3];
    const float* eWhh   = (const float*)d_in[4];
    const float* ebih   = (const float*)d_in[5];
    const float* ebhh   = (const float*)d_in[6];
    const float* to_mu  = (const float*)d_in[7];
    const float* to_ls  = (const float*)d_in[8];
    const float* W1     = (const float*)d_in[9];
    const float* b1     = (const float*)d_in[10];
    const float* W2     = (const float*)d_in[11];
    const float* b2     = (const float*)d_in[12];
    const float* W3     = (const float*)d_in[13];
    const float* b3     = (const float*)d_in[14];
    const float* gWih   = (const float*)d_in[15];
    const float* gWhh   = (const float*)d_in[16];
    const float* gbias  = (const float*)d_in[17];
    float* out = (float*)d_out;
    float* ws  = (float*)d_ws;

    float* henc   = ws;                          // 32768 f
    float* psi2   = ws + 32768;                  // 4096 f
    float* dcarry = ws + 36864;                  // 32768 f
    u16*   psi16  = (u16*)(ws + 69632);          // 24,714,240 B -> ends 6,248,192 f
    u32*   hseq   = (u32*)(ws + 6248192);        // 16,777,216 u32 -> ends 23,025,408 f
    u16*   gbuf   = (u16*)(ws + 23025408);
    const size_t used = (size_t)23025408 * 4;
    size_t avail = (ws_size > used + 4096) ? (ws_size - used - 4096) : 0;
    int ct = (int)(avail / ((size_t)BB * 768 * 2));
    if (ct > TT) ct = TT;
    if (ct < 1) ct = 1;

    for (int t0 = 0; t0 < TT; t0 += ct) {
        const int len = (TT - t0 < ct) ? (TT - t0) : ct;
        const int nt = (len + 127) / 128;
        gemm_x_kernel<<<BB * nt, 768, 0, stream>>>(inputs, eWih, psi16, 0, t0, len, ct, nt, gbuf);
        enc_scan_kernel<<<BB, 512, 0, stream>>>(gbuf, t0, len, ct, eWhh, ebih, ebhh, henc);
    }
    latent_kernel<<<BB, 256, 0, stream>>>(henc, eps, to_mu, to_ls, W1, b1, W2, b2, psi2, out);
    psi3_kernel<<<(NPSI + 255) / 256, 256, 0, stream>>>(psi2, W3, b3, psi16);
    for (int t0 = 0; t0 < TT; t0 += ct) {
        const int len = (TT - t0 < ct) ? (TT - t0) : ct;
        const int nt = (len + 127) / 128;
        gemm_x_kernel<<<BB * nt, 768, 0, stream>>>(inputs, gWih, psi16, 1, t0, len, ct, nt, gbuf);
        dec_scan_kernel<<<BB, 512, 0, stream>>>(gbuf, t0, len, ct, state, gWhh, gbias, psi16,
                                                dcarry, hseq, out);
    }
    yhat_kernel<<<BB * 32, 256, 0, stream>>>(hseq, psi16, out);
    post_kernel<<<BB * 8, 256, 0, stream>>>(inputs, psi16, out);
}